// Round 1
// baseline (451.079 us; speedup 1.0000x reference)
//
#include <hip/hip_runtime.h>

// SSIM loss, fp32, x/y: (32,3,512,512), scalar mean output.
// R3: occupancy round.
//   - RPW 16 -> 8: grid 1536 -> 3072 blocks (12 blocks/CU demand, 8 resident
//     filling all 32 wave slots/CU). Row-overlap refetch cost 10/8 vs 18/16,
//     cheap at 17% HBM utilization.
//   - __launch_bounds__(256, 8): pin compiler under the 64-VGPR occupancy
//     cliff (8 waves/SIMD). Current VGPR count 52 -> headroom.
//   - build_h: prefix-pair trick, 6 adds per 3-tap group of 4 outputs
//     (was 8): 30 adds/iter instead of 40.
//   - Everything else unchanged from R2 (float4-per-lane sliding window,
//     shuffle halos, prefetch distance 1).

#define IMG_H 512
#define IMG_W 512
#define N_PLANES 96                    // 32 * 3
#define TILE_W 256
#define N_TILES 2
#define RPW 8                          // rows per wave
#define WAVES_PER_BLOCK 4
#define ROWS_PER_BLOCK (RPW * WAVES_PER_BLOCK)          // 32
#define BLOCKS_PER_TILE (IMG_H / ROWS_PER_BLOCK)        // 16
#define N_MAIN_BLOCKS (N_PLANES * N_TILES * BLOCKS_PER_TILE)  // 3072
#define TOTAL_ELEMS 25165824.0f        // 32*3*512*512

__device__ __forceinline__ int reflect512(int i) {
    i = i < 0 ? -i : i;
    return i > (IMG_H - 1) ? (2 * (IMG_H - 1) - i) : i;
}

struct Raw {
    float4 xv, yv;   // this lane's 4 columns
    float  xh, yh;   // halo scalar (lane 0: col c0-1, lane 63: col c0+256)
};

struct H {           // horizontal 3-tap sums for this lane's 4 output columns
    float x[4], y[4], xx[4], yy[4], xy[4];
};

__device__ __forceinline__ Raw load_row(const float* __restrict__ px,
                                        const float* __restrict__ py,
                                        int r, int vidx, int lane,
                                        int lh, int rh) {
    const int rr = reflect512(r);
    const size_t rowb = (size_t)rr * IMG_W;
    Raw o;
    o.xv = ((const float4*)(px + rowb))[vidx];
    o.yv = ((const float4*)(py + rowb))[vidx];
    o.xh = 0.0f; o.yh = 0.0f;
    if (lane == 0 || lane == 63) {
        const int hc = (lane == 0) ? lh : rh;
        o.xh = px[rowb + hc];
        o.yh = py[rowb + hc];
    }
    return o;
}

// 3-tap sums of 4 consecutive windows over 6 elements, sharing pair sums:
// o[j] = e[j] + e[j+1] + e[j+2], 6 adds instead of 8.
__device__ __forceinline__ void tri3(const float e[6], float o[4]) {
    const float p12 = e[1] + e[2];
    const float p34 = e[3] + e[4];
    o[0] = e[0] + p12;
    o[1] = p12 + e[3];
    o[2] = e[2] + p34;
    o[3] = p34 + e[5];
}

__device__ __forceinline__ H build_h(const Raw& rw, int lane) {
    // Neighbor edge elements via shuffle; boundary lanes use their halo loads.
    float xm = __shfl_up(rw.xv.w, 1);
    float ym = __shfl_up(rw.yv.w, 1);
    float xp = __shfl_down(rw.xv.x, 1);
    float yp = __shfl_down(rw.yv.x, 1);
    if (lane == 0)  { xm = rw.xh; ym = rw.yh; }
    if (lane == 63) { xp = rw.xh; yp = rw.yh; }

    const float x6[6] = { xm, rw.xv.x, rw.xv.y, rw.xv.z, rw.xv.w, xp };
    const float y6[6] = { ym, rw.yv.x, rw.yv.y, rw.yv.z, rw.yv.w, yp };

    float xx6[6], yy6[6], xy6[6];
    #pragma unroll
    for (int i = 0; i < 6; ++i) {
        xx6[i] = x6[i] * x6[i];
        yy6[i] = y6[i] * y6[i];
        xy6[i] = x6[i] * y6[i];
    }
    H h;
    tri3(x6,  h.x);
    tri3(y6,  h.y);
    tri3(xx6, h.xx);
    tri3(yy6, h.yy);
    tri3(xy6, h.xy);
    return h;
}

__global__ __launch_bounds__(256, 8)
void ssim_main_kernel(const float* __restrict__ x, const float* __restrict__ y,
                      float* __restrict__ partials) {
    const int blk   = blockIdx.x;
    const int plane = blk / (N_TILES * BLOCKS_PER_TILE);
    const int rem   = blk % (N_TILES * BLOCKS_PER_TILE);
    const int tile  = rem / BLOCKS_PER_TILE;
    const int rblk  = rem % BLOCKS_PER_TILE;
    const int wave  = threadIdx.x >> 6;
    const int lane  = threadIdx.x & 63;

    const int c0   = tile * TILE_W;
    const int vidx = (c0 >> 2) + lane;                 // float4 index within row
    const int lh   = reflect512(c0 - 1);               // left halo column
    const int rh   = reflect512(c0 + TILE_W);          // right halo column
    const int r0   = (rblk * WAVES_PER_BLOCK + wave) * RPW;

    const float* px = x + (size_t)plane * (IMG_H * IMG_W);
    const float* py = y + (size_t)plane * (IMG_H * IMG_W);

    const float C1v  = 0.0001f;   // 0.01^2
    const float C2v  = 0.0009f;   // 0.03^2
    const float inv9 = 1.0f / 9.0f;

    Raw ra = load_row(px, py, r0 - 1, vidx, lane, lh, rh);
    Raw rb = load_row(px, py, r0,     vidx, lane, lh, rh);
    Raw rc = load_row(px, py, r0 + 1, vidx, lane, lh, rh);
    H h0 = build_h(ra, lane);
    H h1 = build_h(rb, lane);

    float acc = 0.0f;
    for (int i = 0; i < RPW; ++i) {
        // Prefetch the row needed next iteration (reflect keeps the address
        // in-bounds even past the image; last prefetch is unused).
        Raw rd = load_row(px, py, r0 + 2 + i, vidx, lane, lh, rh);

        H h2 = build_h(rc, lane);

        #pragma unroll
        for (int j = 0; j < 4; ++j) {
            const float sx  = h0.x[j]  + h1.x[j]  + h2.x[j];
            const float sy  = h0.y[j]  + h1.y[j]  + h2.y[j];
            const float sxx = h0.xx[j] + h1.xx[j] + h2.xx[j];
            const float syy = h0.yy[j] + h1.yy[j] + h2.yy[j];
            const float sxy = h0.xy[j] + h1.xy[j] + h2.xy[j];

            const float mux   = sx * inv9;
            const float muy   = sy * inv9;
            const float mux2  = mux * mux;
            const float muy2  = muy * muy;
            const float muxy  = mux * muy;
            const float sigx  = fmaf(sxx, inv9, -mux2);
            const float sigy  = fmaf(syy, inv9, -muy2);
            const float sigxy = fmaf(sxy, inv9, -muxy);

            const float nume = (2.0f * muxy + C1v) * (2.0f * sigxy + C2v);
            const float deno = (mux2 + muy2 + C1v) * (sigx + sigy + C2v);
            float v = fmaf(nume, -__builtin_amdgcn_rcpf(deno), 1.0f) * 0.5f;
            v = fminf(fmaxf(v, 0.0f), 1.0f);
            acc += v;
        }

        h0 = h1;
        h1 = h2;
        rc = rd;
    }

    #pragma unroll
    for (int off = 32; off > 0; off >>= 1)
        acc += __shfl_down(acc, off);

    __shared__ float wave_sums[WAVES_PER_BLOCK];
    if (lane == 0) wave_sums[wave] = acc;
    __syncthreads();
    if (threadIdx.x == 0)
        partials[blk] = wave_sums[0] + wave_sums[1] + wave_sums[2] + wave_sums[3];
}

__global__ void ssim_reduce_kernel(const float* __restrict__ partials,
                                   float* __restrict__ out) {
    float acc = 0.0f;
    for (int i = threadIdx.x; i < N_MAIN_BLOCKS; i += 256)
        acc += partials[i];
    #pragma unroll
    for (int off = 32; off > 0; off >>= 1)
        acc += __shfl_down(acc, off);
    __shared__ float wave_sums[4];
    const int wave = threadIdx.x >> 6;
    const int lane = threadIdx.x & 63;
    if (lane == 0) wave_sums[wave] = acc;
    __syncthreads();
    if (threadIdx.x == 0)
        out[0] = (wave_sums[0] + wave_sums[1] + wave_sums[2] + wave_sums[3])
                 * (1.0f / TOTAL_ELEMS);
}

extern "C" void kernel_launch(void* const* d_in, const int* in_sizes, int n_in,
                              void* d_out, int out_size, void* d_ws, size_t ws_size,
                              hipStream_t stream) {
    const float* x = (const float*)d_in[0];
    const float* y = (const float*)d_in[1];
    float* out      = (float*)d_out;
    float* partials = (float*)d_ws;   // N_MAIN_BLOCKS floats (12 KiB)

    ssim_main_kernel<<<N_MAIN_BLOCKS, 256, 0, stream>>>(x, y, partials);
    ssim_reduce_kernel<<<1, 256, 0, stream>>>(partials, out);
}

// Round 2
// 220.659 us; speedup vs baseline: 2.0442x; 2.0442x over previous
//
#include <hip/hip_runtime.h>

// SSIM loss, fp32, x/y: (32,3,512,512), scalar mean output.
// R4: R3 post-mortem fix.
//   - R3's __launch_bounds__(256,8) forced VGPR 52->32 and spilled the rolling
//     window to scratch (WRITE_SIZE 48KB -> 601MB, VALUBusy 42->11%). Revert
//     to (256,4): 52 VGPRs is already under the 64-VGPR occupancy step, so
//     8 waves/SIMD were never register-limited -- only grid-limited.
//   - Keep RPW=8: grid 1536 -> 3072 blocks (12 blocks/CU demand) is the part
//     of R3 that actually attacks the latency-bound profile of R2.
//   - Keep tri3 prefix-pair horizontal sums (30 adds/iter vs 40).

#define IMG_H 512
#define IMG_W 512
#define N_PLANES 96                    // 32 * 3
#define TILE_W 256
#define N_TILES 2
#define RPW 8                          // rows per wave
#define WAVES_PER_BLOCK 4
#define ROWS_PER_BLOCK (RPW * WAVES_PER_BLOCK)          // 32
#define BLOCKS_PER_TILE (IMG_H / ROWS_PER_BLOCK)        // 16
#define N_MAIN_BLOCKS (N_PLANES * N_TILES * BLOCKS_PER_TILE)  // 3072
#define TOTAL_ELEMS 25165824.0f        // 32*3*512*512

__device__ __forceinline__ int reflect512(int i) {
    i = i < 0 ? -i : i;
    return i > (IMG_H - 1) ? (2 * (IMG_H - 1) - i) : i;
}

struct Raw {
    float4 xv, yv;   // this lane's 4 columns
    float  xh, yh;   // halo scalar (lane 0: col c0-1, lane 63: col c0+256)
};

struct H {           // horizontal 3-tap sums for this lane's 4 output columns
    float x[4], y[4], xx[4], yy[4], xy[4];
};

__device__ __forceinline__ Raw load_row(const float* __restrict__ px,
                                        const float* __restrict__ py,
                                        int r, int vidx, int lane,
                                        int lh, int rh) {
    const int rr = reflect512(r);
    const size_t rowb = (size_t)rr * IMG_W;
    Raw o;
    o.xv = ((const float4*)(px + rowb))[vidx];
    o.yv = ((const float4*)(py + rowb))[vidx];
    o.xh = 0.0f; o.yh = 0.0f;
    if (lane == 0 || lane == 63) {
        const int hc = (lane == 0) ? lh : rh;
        o.xh = px[rowb + hc];
        o.yh = py[rowb + hc];
    }
    return o;
}

// 3-tap sums of 4 consecutive windows over 6 elements, sharing pair sums:
// o[j] = e[j] + e[j+1] + e[j+2], 6 adds instead of 8.
__device__ __forceinline__ void tri3(const float e[6], float o[4]) {
    const float p12 = e[1] + e[2];
    const float p34 = e[3] + e[4];
    o[0] = e[0] + p12;
    o[1] = p12 + e[3];
    o[2] = e[2] + p34;
    o[3] = p34 + e[5];
}

__device__ __forceinline__ H build_h(const Raw& rw, int lane) {
    // Neighbor edge elements via shuffle; boundary lanes use their halo loads.
    float xm = __shfl_up(rw.xv.w, 1);
    float ym = __shfl_up(rw.yv.w, 1);
    float xp = __shfl_down(rw.xv.x, 1);
    float yp = __shfl_down(rw.yv.x, 1);
    if (lane == 0)  { xm = rw.xh; ym = rw.yh; }
    if (lane == 63) { xp = rw.xh; yp = rw.yh; }

    const float x6[6] = { xm, rw.xv.x, rw.xv.y, rw.xv.z, rw.xv.w, xp };
    const float y6[6] = { ym, rw.yv.x, rw.yv.y, rw.yv.z, rw.yv.w, yp };

    float xx6[6], yy6[6], xy6[6];
    #pragma unroll
    for (int i = 0; i < 6; ++i) {
        xx6[i] = x6[i] * x6[i];
        yy6[i] = y6[i] * y6[i];
        xy6[i] = x6[i] * y6[i];
    }
    H h;
    tri3(x6,  h.x);
    tri3(y6,  h.y);
    tri3(xx6, h.xx);
    tri3(yy6, h.yy);
    tri3(xy6, h.xy);
    return h;
}

__global__ __launch_bounds__(256, 4)
void ssim_main_kernel(const float* __restrict__ x, const float* __restrict__ y,
                      float* __restrict__ partials) {
    const int blk   = blockIdx.x;
    const int plane = blk / (N_TILES * BLOCKS_PER_TILE);
    const int rem   = blk % (N_TILES * BLOCKS_PER_TILE);
    const int tile  = rem / BLOCKS_PER_TILE;
    const int rblk  = rem % BLOCKS_PER_TILE;
    const int wave  = threadIdx.x >> 6;
    const int lane  = threadIdx.x & 63;

    const int c0   = tile * TILE_W;
    const int vidx = (c0 >> 2) + lane;                 // float4 index within row
    const int lh   = reflect512(c0 - 1);               // left halo column
    const int rh   = reflect512(c0 + TILE_W);          // right halo column
    const int r0   = (rblk * WAVES_PER_BLOCK + wave) * RPW;

    const float* px = x + (size_t)plane * (IMG_H * IMG_W);
    const float* py = y + (size_t)plane * (IMG_H * IMG_W);

    const float C1v  = 0.0001f;   // 0.01^2
    const float C2v  = 0.0009f;   // 0.03^2
    const float inv9 = 1.0f / 9.0f;

    Raw ra = load_row(px, py, r0 - 1, vidx, lane, lh, rh);
    Raw rb = load_row(px, py, r0,     vidx, lane, lh, rh);
    Raw rc = load_row(px, py, r0 + 1, vidx, lane, lh, rh);
    H h0 = build_h(ra, lane);
    H h1 = build_h(rb, lane);

    float acc = 0.0f;
    for (int i = 0; i < RPW; ++i) {
        // Prefetch the row needed next iteration (reflect keeps the address
        // in-bounds even past the image; last prefetch is unused).
        Raw rd = load_row(px, py, r0 + 2 + i, vidx, lane, lh, rh);

        H h2 = build_h(rc, lane);

        #pragma unroll
        for (int j = 0; j < 4; ++j) {
            const float sx  = h0.x[j]  + h1.x[j]  + h2.x[j];
            const float sy  = h0.y[j]  + h1.y[j]  + h2.y[j];
            const float sxx = h0.xx[j] + h1.xx[j] + h2.xx[j];
            const float syy = h0.yy[j] + h1.yy[j] + h2.yy[j];
            const float sxy = h0.xy[j] + h1.xy[j] + h2.xy[j];

            const float mux   = sx * inv9;
            const float muy   = sy * inv9;
            const float mux2  = mux * mux;
            const float muy2  = muy * muy;
            const float muxy  = mux * muy;
            const float sigx  = fmaf(sxx, inv9, -mux2);
            const float sigy  = fmaf(syy, inv9, -muy2);
            const float sigxy = fmaf(sxy, inv9, -muxy);

            const float nume = (2.0f * muxy + C1v) * (2.0f * sigxy + C2v);
            const float deno = (mux2 + muy2 + C1v) * (sigx + sigy + C2v);
            float v = fmaf(nume, -__builtin_amdgcn_rcpf(deno), 1.0f) * 0.5f;
            v = fminf(fmaxf(v, 0.0f), 1.0f);
            acc += v;
        }

        h0 = h1;
        h1 = h2;
        rc = rd;
    }

    #pragma unroll
    for (int off = 32; off > 0; off >>= 1)
        acc += __shfl_down(acc, off);

    __shared__ float wave_sums[WAVES_PER_BLOCK];
    if (lane == 0) wave_sums[wave] = acc;
    __syncthreads();
    if (threadIdx.x == 0)
        partials[blk] = wave_sums[0] + wave_sums[1] + wave_sums[2] + wave_sums[3];
}

__global__ void ssim_reduce_kernel(const float* __restrict__ partials,
                                   float* __restrict__ out) {
    float acc = 0.0f;
    for (int i = threadIdx.x; i < N_MAIN_BLOCKS; i += 256)
        acc += partials[i];
    #pragma unroll
    for (int off = 32; off > 0; off >>= 1)
        acc += __shfl_down(acc, off);
    __shared__ float wave_sums[4];
    const int wave = threadIdx.x >> 6;
    const int lane = threadIdx.x & 63;
    if (lane == 0) wave_sums[wave] = acc;
    __syncthreads();
    if (threadIdx.x == 0)
        out[0] = (wave_sums[0] + wave_sums[1] + wave_sums[2] + wave_sums[3])
                 * (1.0f / TOTAL_ELEMS);
}

extern "C" void kernel_launch(void* const* d_in, const int* in_sizes, int n_in,
                              void* d_out, int out_size, void* d_ws, size_t ws_size,
                              hipStream_t stream) {
    const float* x = (const float*)d_in[0];
    const float* y = (const float*)d_in[1];
    float* out      = (float*)d_out;
    float* partials = (float*)d_ws;   // N_MAIN_BLOCKS floats (12 KiB)

    ssim_main_kernel<<<N_MAIN_BLOCKS, 256, 0, stream>>>(x, y, partials);
    ssim_reduce_kernel<<<1, 256, 0, stream>>>(partials, out);
}